// Round 1
// 261.685 us; speedup vs baseline: 1.0206x; 1.0206x over previous
//
#include <hip/hip_runtime.h>
#include <hip/hip_bf16.h>

#define B_  8
#define S_  2048
#define H_  6
#define DK_ 24
#define DM_ 144

// tanh(SCALE*c) ~= c*(K0 + K1*t + K2*t^2), t = c^2, SCALE = 0.1/sqrt(24).
#define TK0  2.0412414523193153e-02f
#define TK1 -2.8350575726379381e-06f
#define TK2  4.7250959543965635e-10f

typedef __bf16 bf16x8 __attribute__((ext_vector_type(8)));
typedef __bf16 bf16x2 __attribute__((ext_vector_type(2)));
typedef float  f32x4  __attribute__((ext_vector_type(4)));
typedef float  f32x2  __attribute__((ext_vector_type(2)));

#define MFMA_ __builtin_amdgcn_mfma_f32_16x16x32_bf16

__device__ __forceinline__ unsigned short f2bf(float f) {
    return __builtin_bit_cast(unsigned short, (__bf16)f);
}
__device__ __forceinline__ uint pack2(float a, float b) {
    bf16x2 v; v[0] = (__bf16)a; v[1] = (__bf16)b;
    return __builtin_bit_cast(uint, v);
}
// packed tanh on a pair -> packed bf16 word.  float2 arith lowers to
// v_pk_mul_f32 / v_pk_fma_f32 on gfx950 (half the VALU issue of scalar).
__device__ __forceinline__ uint tanh2_pack(float a, float b) {
    f32x2 c; c[0] = a; c[1] = b;
    f32x2 t = c * c;
    f32x2 u = t * TK2 + TK1;
    u = t * u + TK0;
    f32x2 r = c * u;
    return pack2(r[0], r[1]);
}

// ---------------------------------------------------------------------------
// prep: fused weight prep + K/V retile (one dispatch).
// blocks 0..1535   : K f32 -> Ktt[bh][kt][64 s][32 dk] bf16 (cols 24..31 zero)
//                    V f32 -> Vtt[bh][kt][32 d][64 s] bf16 (rows 24..31 zero)
// blocks 1536..1745: Whq[6][32][160] bf16 (head-sliced Wq, bias at k=144) and
//                    Wlp[144][160] bf16 (lin_w, bias at k=144).
// ---------------------------------------------------------------------------
__global__ __launch_bounds__(256)
void prep_kernel(const float* __restrict__ K, const float* __restrict__ V,
                 const float* __restrict__ Wq, const float* __restrict__ Wqb,
                 const float* __restrict__ Wl, const float* __restrict__ lb,
                 ushort* __restrict__ Ktt, ushort* __restrict__ Vtt,
                 ushort* __restrict__ Whq, ushort* __restrict__ Wlp) {
    __shared__ float sv[64 * 25];
    const int t = threadIdx.x;
    const int bid = blockIdx.x;
    if (bid >= 1536) {                        // ---- weight part ----
        int i = (bid - 1536) * 256 + t;
        if (i < 30720) {                      // Whq: 6*32*160
            int h = i / 5120, rem = i % 5120;
            int d = rem / 160, c = rem % 160;
            float v = 0.f;
            if (d < DK_) {
                if (c < DM_)       v = Wq[(h * DK_ + d) * DM_ + c];
                else if (c == DM_) v = Wqb[h * DK_ + d];
            }
            Whq[i] = f2bf(v);
        } else if (i < 53760) {               // Wlp: 144*160
            int j = i - 30720;
            int r = j / 160, c = j % 160;
            float v = (c < DM_) ? Wl[r * DM_ + c] : (c == DM_ ? lb[r] : 0.f);
            Wlp[j] = f2bf(v);
        }
        return;
    }
    // ---- KV part ----
    const int kt = bid & 31, h = (bid >> 5) % H_, b = bid / (32 * H_);
    const int bh = b * H_ + h;
    const size_t tile = (size_t)(bh * 32 + kt);
    const float4* Ks = (const float4*)(K + ((size_t)bh * S_ + kt * 64) * DK_);
    ushort* Ko = Ktt + tile * 2048;
    for (int idx = t; idx < 384; idx += 256) {
        int r = idx / 6, c4 = (idx % 6) * 4;
        float4 v = Ks[idx];
        ushort4 u; u.x = f2bf(v.x); u.y = f2bf(v.y); u.z = f2bf(v.z); u.w = f2bf(v.w);
        *(ushort4*)&Ko[r * 32 + c4] = u;
    }
    if (t < 64) { uint4 z = {0u,0u,0u,0u}; *(uint4*)&Ko[t * 32 + 24] = z; }
    const float4* Vs = (const float4*)(V + ((size_t)bh * S_ + kt * 64) * DK_);
    for (int idx = t; idx < 384; idx += 256) {
        int r = idx / 6, c4 = (idx % 6) * 4;
        *(float4*)&sv[r * 25 + c4] = Vs[idx];
    }
    __syncthreads();
    int d = t >> 3, s8 = (t & 7) * 8;
    uint4 o = {0u,0u,0u,0u};
    if (d < DK_) {
        o.x = pack2(sv[(s8 + 0) * 25 + d], sv[(s8 + 1) * 25 + d]);
        o.y = pack2(sv[(s8 + 2) * 25 + d], sv[(s8 + 3) * 25 + d]);
        o.z = pack2(sv[(s8 + 4) * 25 + d], sv[(s8 + 5) * 25 + d]);
        o.w = pack2(sv[(s8 + 6) * 25 + d], sv[(s8 + 7) * 25 + d]);
    }
    ((uint4*)Vtt)[tile * 256 + t] = o;
}

// ---------------------------------------------------------------------------
// attn: fused qproj + tanh-attention.
// Block = 512 threads (8 waves) = 128 q-rows of one (b,h); wave owns 16 rows.
// Grid 768 = 3 blocks/CU, LDS 48.1KB -> all resident: 24 waves/CU.
// K/V LDS double-buffer, ONE barrier per k-tile; staging split: waves 0-3
// stage K, waves 4-7 stage V (1 uint4 load+store per thread per tile).
// Output: bf16 ctx tile into Cb[16384][160] (outln-staging layout).
// ---------------------------------------------------------------------------
__global__ __launch_bounds__(512, 6)
void attn_kernel(const float* __restrict__ Q, const ushort* __restrict__ Whq,
                 const ushort* __restrict__ Ktt, const ushort* __restrict__ Vtt,
                 ushort* __restrict__ Cb) {
    __shared__ __attribute__((aligned(16))) char smem[48128];
    ushort* s_q  = (ushort*)smem;             // 128 x pitch40   [0, 10240)
    ushort* s_k  = (ushort*)(smem + 10240);   // 2 x 64 x pitch40 [10240, 20480)
    ushort* s_vt = (ushort*)(smem + 20480);   // 2 x 32 x pitch72 [20480, 29696)
    ushort* s_p  = (ushort*)(smem + 29696);   // 8w x 16 x pitch72 [29696, 48128)
    float*  s_ctx = (float*)smem;             // epilogue alias: 128 x 28 f32

    const int t = threadIdx.x;
    const int w = t >> 6, n16 = t & 15, g = (t >> 4) & 3;
    const int qp = blockIdx.x, h = blockIdx.y, b = blockIdx.z;
    const int bh = b * H_ + h;
    const int row0 = qp * 128;

    const uint4* Kb4 = (const uint4*)Ktt + (size_t)bh * 8192;   // 32 tiles x 256
    const uint4* Vb4 = (const uint4*)Vtt + (size_t)bh * 8192;

    // staging role: waves 0-3 -> K (t<256), waves 4-7 -> V
    const int t2 = t & 255;
    const int stoff = (t < 256) ? ((t2 >> 2) * 40 + (t2 & 3) * 8)
                                : ((t2 >> 3) * 72 + (t2 & 7) * 8);
    uint4 sreg = (t < 256) ? Kb4[t2] : Vb4[t2];       // preload tile 0

    // ---- Phase A: q = Q @ Whq^T + bias (k=144 col), frags from global ----
    const f32x4 zf = {0.f, 0.f, 0.f, 0.f};
    const uint4* Wh4 = (const uint4*)Whq + h * 640;
    {
        const float* Qr = Q + (size_t)(b * S_ + row0 + w * 16 + n16) * DM_;
        f32x4 qa0 = zf, qa1 = zf;
#pragma unroll
        for (int ks = 0; ks < 5; ++ks) {
            bf16x8 av;
            if (ks < 4 || g < 2) {            // real cols (ks=4,g<2 -> 128..143)
                float4 f0 = *(const float4*)&Qr[ks * 32 + g * 8];
                float4 f1 = *(const float4*)&Qr[ks * 32 + g * 8 + 4];
                uint4 u;
                u.x = pack2(f0.x, f0.y); u.y = pack2(f0.z, f0.w);
                u.z = pack2(f1.x, f1.y); u.w = pack2(f1.z, f1.w);
                av = __builtin_bit_cast(bf16x8, u);
            } else {                          // k=144 bias col (g==2), zeros (g==3)
                uint4 u = {0u, 0u, 0u, 0u};
                if (g == 2) u.x = 0x00003F80u;
                av = __builtin_bit_cast(bf16x8, u);
            }
            bf16x8 bv0 = __builtin_bit_cast(bf16x8, Wh4[n16 * 20 + ks * 4 + g]);
            bf16x8 bv1 = __builtin_bit_cast(bf16x8, Wh4[(16 + n16) * 20 + ks * 4 + g]);
            qa0 = MFMA_(av, bv0, qa0, 0, 0, 0);
            qa1 = MFMA_(av, bv1, qa1, 0, 0, 0);
        }
#pragma unroll
        for (int reg = 0; reg < 4; ++reg) {   // wave-local transpose (no barrier)
            int r = (w * 16 + g * 4 + reg) * 40;
            s_q[r + n16]      = f2bf(qa0[reg]);
            s_q[r + 16 + n16] = f2bf(qa1[reg]);   // d 24..31 zero via Whq rows
        }
    }
    const bf16x8 qf = *(const bf16x8*)&s_q[(w * 16 + n16) * 40 + g * 8];

    // ---- k-tile loop: double-buffered LDS, one barrier per tile ----------
    ushort* s_pw = s_p + w * 1152;            // wave-private P: 16 x pitch72
    const int prow = n16 * 72;
    const int aoff = n16 * 40 + g * 8;        // hoisted LDS read offsets
    const int voff = n16 * 72 + g * 8;
    f32x4 acc0 = zf, acc1 = zf;
    // explicit double-buffer pointers (swap each tile)
    ushort* stb_a = ((t < 256) ? s_k : s_vt) + stoff;
    ushort* stb_b = stb_a + ((t < 256) ? 2560 : 2304);
    const ushort* ka = s_k;  const ushort* kb = s_k + 2560;
    const ushort* va = s_vt; const ushort* vbp = s_vt + 2304;
    for (int kt = 0; kt < 32; ++kt) {
        *(uint4*)stb_a = sreg;
        __syncthreads();
        {   // prefetch next tile AFTER the barrier
            int nt = ((kt + 1) & 31) * 256;
            sreg = (t < 256) ? Kb4[nt + t2] : Vb4[nt + t2];
        }
        // S strips + tanh -> P (wave-private)
        bf16x8 a0 = *(const bf16x8*)&ka[aoff];
        bf16x8 a1 = *(const bf16x8*)&ka[640 + aoff];
        bf16x8 a2 = *(const bf16x8*)&ka[1280 + aoff];
        bf16x8 a3 = *(const bf16x8*)&ka[1920 + aoff];
        __builtin_amdgcn_s_setprio(1);
        f32x4 c0 = MFMA_(a0, qf, zf, 0, 0, 0);
        f32x4 c1 = MFMA_(a1, qf, zf, 0, 0, 0);
        f32x4 c2 = MFMA_(a2, qf, zf, 0, 0, 0);
        f32x4 c3 = MFMA_(a3, qf, zf, 0, 0, 0);
        __builtin_amdgcn_s_setprio(0);
        uint2 u;
        u.x = tanh2_pack(c0[0], c0[1]);
        u.y = tanh2_pack(c0[2], c0[3]);
        *(uint2*)&s_pw[prow + 0  + g * 4] = u;
        u.x = tanh2_pack(c1[0], c1[1]);
        u.y = tanh2_pack(c1[2], c1[3]);
        *(uint2*)&s_pw[prow + 16 + g * 4] = u;
        u.x = tanh2_pack(c2[0], c2[1]);
        u.y = tanh2_pack(c2[2], c2[3]);
        *(uint2*)&s_pw[prow + 32 + g * 4] = u;
        u.x = tanh2_pack(c3[0], c3[1]);
        u.y = tanh2_pack(c3[2], c3[3]);
        *(uint2*)&s_pw[prow + 48 + g * 4] = u;
        // PV (wave-local P; DS ops in-order per wave)
        bf16x8 ap0 = *(const bf16x8*)&s_pw[prow + g * 8];
        bf16x8 ap1 = *(const bf16x8*)&s_pw[prow + 32 + g * 8];
        bf16x8 vb00 = *(const bf16x8*)&va[voff];
        bf16x8 vb01 = *(const bf16x8*)&va[voff + 32];
        bf16x8 vb10 = *(const bf16x8*)&va[1152 + voff];
        bf16x8 vb11 = *(const bf16x8*)&va[1152 + voff + 32];
        __builtin_amdgcn_s_setprio(1);
        acc0 = MFMA_(ap0, vb00, acc0, 0, 0, 0);
        acc0 = MFMA_(ap1, vb01, acc0, 0, 0, 0);
        acc1 = MFMA_(ap0, vb10, acc1, 0, 0, 0);
        acc1 = MFMA_(ap1, vb11, acc1, 0, 0, 0);
        __builtin_amdgcn_s_setprio(0);
        // swap double-buffer pointers
        { ushort* tp = stb_a; stb_a = stb_b; stb_b = tp; }
        { const ushort* tp = ka; ka = kb; kb = tp; }
        { const ushort* tp = va; va = vbp; vbp = tp; }
    }

    // ---- epilogue: ctx -> Cb bf16 (s_ctx aliases s_q/s_k; barrier both) ---
    __syncthreads();
#pragma unroll
    for (int reg = 0; reg < 4; ++reg) {
        int row = w * 16 + g * 4 + reg;
        s_ctx[row * 28 + n16] = acc0[reg];
        if (n16 < 8) s_ctx[row * 28 + 16 + n16] = acc1[reg];
    }
    __syncthreads();
    if (t < 384) {
        int r = t / 3, c = t % 3;             // 3 x uint4 (8 bf16) per row
        const float* src = &s_ctx[r * 28 + c * 8];
        uint4 u;
        u.x = pack2(src[0], src[1]); u.y = pack2(src[2], src[3]);
        u.z = pack2(src[4], src[5]); u.w = pack2(src[6], src[7]);
        *(uint4*)&Cb[(size_t)(b * S_ + row0 + r) * 160 + h * 24 + c * 8] = u;
    }
}

// ---------------------------------------------------------------------------
// outln: out = LN(ctx @ Wl^T + lb + residual) * g + beta.
// ctx comes in as bf16 Cb[16384][160] -> pure uint4 LDS staging.
// ---------------------------------------------------------------------------
__global__ __launch_bounds__(512)
void outln_kernel(const float* __restrict__ Qres, const ushort* __restrict__ Wlp,
                  const ushort* __restrict__ Cb,
                  const float* __restrict__ lg, const float* __restrict__ lbeta,
                  float* __restrict__ io) {
    __shared__ __attribute__((aligned(16))) ushort s_a[64 * 168];
    __shared__ __attribute__((aligned(16))) ushort s_w[144 * 168];
    __shared__ float s_red[2][2][64];
    const int t = threadIdx.x;
    const int w = t >> 6, n16 = t & 15, g = (t >> 4) & 3;
    const int wq = w & 3, half = w >> 2;
    const int nt_base = half * 5, nt_cnt = half ? 4 : 5;
    const int row0 = blockIdx.x * 64;

    const ushort* Cr = Cb + (size_t)row0 * 160;
    for (int idx = t; idx < 1152; idx += 512) {     // cols 0..143 only
        int r = idx / 18, c8 = (idx % 18) * 8;
        *(uint4*)&s_a[r * 168 + c8] = *(const uint4*)&Cr[r * 160 + c8];
    }
    if (t < 64) {
        uint4 pad = {0x00003F80u, 0u, 0u, 0u};
        uint4 z4  = {0u, 0u, 0u, 0u};
        *(uint4*)&s_a[t * 168 + 144] = pad;
        *(uint4*)&s_a[t * 168 + 152] = z4;
    }
    for (int idx = t; idx < 2880; idx += 512) {
        int r = idx / 20, c8 = (idx % 20) * 8;
        *(uint4*)&s_w[r * 168 + c8] = *(const uint4*)&Wlp[r * 160 + c8];
    }
    __syncthreads();

    f32x4 acc[5];
#pragma unroll
    for (int j = 0; j < 5; ++j) acc[j] = (f32x4){0.f, 0.f, 0.f, 0.f};
#pragma unroll
    for (int ks = 0; ks < 5; ++ks) {
        bf16x8 av = *(const bf16x8*)&s_a[(wq * 16 + n16) * 168 + ks * 32 + g * 8];
        for (int j = 0; j < nt_cnt; ++j) {
            bf16x8 bv = *(const bf16x8*)&s_w[((nt_base + j) * 16 + n16) * 168 + ks * 32 + g * 8];
            acc[j] = MFMA_(av, bv, acc[j], 0, 0, 0);
        }
    }
    float vals[5][4], s1[4] = {0, 0, 0, 0}, s2[4] = {0, 0, 0, 0};
    for (int j = 0; j < nt_cnt; ++j) {
        int d = (nt_base + j) * 16 + n16;
#pragma unroll
        for (int reg = 0; reg < 4; ++reg) {
            int row = row0 + wq * 16 + g * 4 + reg;
            float v = acc[j][reg] + Qres[(size_t)row * DM_ + d];
            vals[j][reg] = v;
            s1[reg] += v; s2[reg] = fmaf(v, v, s2[reg]);
        }
    }
#pragma unroll
    for (int off = 1; off < 16; off <<= 1) {
#pragma unroll
        for (int reg = 0; reg < 4; ++reg) {
            s1[reg] += __shfl_xor(s1[reg], off);
            s2[reg] += __shfl_xor(s2[reg], off);
        }
    }
    if (n16 == 0) {
#pragma unroll
        for (int reg = 0; reg < 4; ++reg) {
            int rr = wq * 16 + g * 4 + reg;
            s_red[half][0][rr] = s1[reg];
            s_red[half][1][rr] = s2[reg];
        }
    }
    __syncthreads();
    float mu[4], rs[4];
#pragma unroll
    for (int reg = 0; reg < 4; ++reg) {
        int rr = wq * 16 + g * 4 + reg;
        float S1 = s_red[0][0][rr] + s_red[1][0][rr];
        float S2 = s_red[0][1][rr] + s_red[1][1][rr];
        float m = S1 * (1.f / 144.f);
        mu[reg] = m;
        rs[reg] = rsqrtf(S2 * (1.f / 144.f) - m * m + 1e-5f);
    }
    for (int j = 0; j < nt_cnt; ++j) {
        int d = (nt_base + j) * 16 + n16;
        float gv = lg[d], bv = lbeta[d];
#pragma unroll
        for (int reg = 0; reg < 4; ++reg) {
            int row = row0 + wq * 16 + g * 4 + reg;
            io[(size_t)row * DM_ + d] = (vals[j][reg] - mu[reg]) * rs[reg] * gv + bv;
        }
    }
}

// ---------------------------------------------------------------------------
extern "C" void kernel_launch(void* const* d_in, const int* in_sizes, int n_in,
                              void* d_out, int out_size, void* d_ws, size_t ws_size,
                              hipStream_t stream) {
    const float* Q     = (const float*)d_in[0];
    const float* K     = (const float*)d_in[1];
    const float* V     = (const float*)d_in[2];
    // d_in[3] = attn_mask: dead code in the reference, ignored.
    const float* Wq_w  = (const float*)d_in[4];
    const float* Wq_b  = (const float*)d_in[5];
    const float* lin_w = (const float*)d_in[6];
    const float* lin_b = (const float*)d_in[7];
    const float* ln_g  = (const float*)d_in[8];
    const float* ln_b  = (const float*)d_in[9];
    float* out = (float*)d_out;

    ushort* Ktt = (ushort*)d_ws;                            // 6,291,456 B
    ushort* Vtt = (ushort*)((char*)d_ws + 6291456);         // 6,291,456 B
    ushort* Whq = (ushort*)((char*)d_ws + 12582912);        // 61,440 B
    ushort* Wlp = (ushort*)((char*)d_ws + 12644352);        // 46,080 B
    ushort* Cb  = (ushort*)((char*)d_ws + 12690432);        // 5,242,880 B

    prep_kernel<<<1746, 256, 0, stream>>>(K, V, Wq_w, Wq_b, lin_w, lin_b,
                                          Ktt, Vtt, Whq, Wlp);
    attn_kernel<<<dim3(S_ / 128, H_, B_), 512, 0, stream>>>(Q, Whq, Ktt, Vtt, Cb);
    outln_kernel<<<(B_ * S_) / 64, 512, 0, stream>>>(Q, Wlp, Cb, ln_g, ln_b, out);
}

// Round 2
// 255.899 us; speedup vs baseline: 1.0436x; 1.0226x over previous
//
#include <hip/hip_runtime.h>
#include <hip/hip_bf16.h>

#define B_  8
#define S_  2048
#define H_  6
#define DK_ 24
#define DM_ 144

// tanh(SCALE*c) ~= c*(K0 + K1*t + K2*t^2), t = c^2, SCALE = 0.1/sqrt(24).
#define TK0  2.0412414523193153e-02f
#define TK1 -2.8350575726379381e-06f
#define TK2  4.7250959543965635e-10f

typedef __bf16 bf16x8 __attribute__((ext_vector_type(8)));
typedef __bf16 bf16x2 __attribute__((ext_vector_type(2)));
typedef float  f32x4  __attribute__((ext_vector_type(4)));
typedef float  f32x2  __attribute__((ext_vector_type(2)));

#define MFMA_ __builtin_amdgcn_mfma_f32_16x16x32_bf16

__device__ __forceinline__ unsigned short f2bf(float f) {
    return __builtin_bit_cast(unsigned short, (__bf16)f);
}
__device__ __forceinline__ uint pack2(float a, float b) {
    bf16x2 v; v[0] = (__bf16)a; v[1] = (__bf16)b;
    return __builtin_bit_cast(uint, v);
}
// packed tanh on a pair -> packed bf16 word (v_pk_mul_f32 / v_pk_fma_f32).
__device__ __forceinline__ uint tanh2_pack(float a, float b) {
    f32x2 c; c[0] = a; c[1] = b;
    f32x2 t = c * c;
    f32x2 u = t * TK2 + TK1;
    u = t * u + TK0;
    f32x2 r = c * u;
    return pack2(r[0], r[1]);
}

// lane-bit-5 swap: x' <- lower-32-half data of {x,y}; y' <- upper-half data.
__device__ __forceinline__ void swap32(uint &x, uint &y) {
    auto r = __builtin_amdgcn_permlane32_swap(x, y, false, false);
    x = r[0]; y = r[1];
}
// lane-bit-4 swap: x' <- bit4==0 data of {x,y}; y' <- bit4==1 data.
__device__ __forceinline__ void swap16(uint &x, uint &y, bool hi16) {
#if __has_builtin(__builtin_amdgcn_permlane16_swap)
    (void)hi16;
    auto r = __builtin_amdgcn_permlane16_swap(x, y, false, false);
    x = r[0]; y = r[1];
#else
    uint xs = __builtin_amdgcn_ds_swizzle(x, 0x401F);   // lane ^ 16
    uint ys = __builtin_amdgcn_ds_swizzle(y, 0x401F);
    uint nx = hi16 ? ys : x;
    uint ny = hi16 ? y : xs;
    x = nx; y = ny;
#endif
}

// ---------------------------------------------------------------------------
// prep: fused weight prep + K/V retile (one dispatch).
// blocks 0..1535   : K f32 -> Ktt[bh][kt][64 s][32 dk] bf16 (cols 24..31 zero)
//                    V f32 -> Vtt[bh][kt][32 d][64 s] bf16 (rows 24..31 zero)
// blocks 1536..1745: Whq[6][32][160] bf16 (head-sliced Wq, bias at k=144) and
//                    Wlp[144][160] bf16 (lin_w, bias at k=144).
// ---------------------------------------------------------------------------
__global__ __launch_bounds__(256)
void prep_kernel(const float* __restrict__ K, const float* __restrict__ V,
                 const float* __restrict__ Wq, const float* __restrict__ Wqb,
                 const float* __restrict__ Wl, const float* __restrict__ lb,
                 ushort* __restrict__ Ktt, ushort* __restrict__ Vtt,
                 ushort* __restrict__ Whq, ushort* __restrict__ Wlp) {
    __shared__ float sv[64 * 25];
    const int t = threadIdx.x;
    const int bid = blockIdx.x;
    if (bid >= 1536) {                        // ---- weight part ----
        int i = (bid - 1536) * 256 + t;
        if (i < 30720) {                      // Whq: 6*32*160
            int h = i / 5120, rem = i % 5120;
            int d = rem / 160, c = rem % 160;
            float v = 0.f;
            if (d < DK_) {
                if (c < DM_)       v = Wq[(h * DK_ + d) * DM_ + c];
                else if (c == DM_) v = Wqb[h * DK_ + d];
            }
            Whq[i] = f2bf(v);
        } else if (i < 53760) {               // Wlp: 144*160
            int j = i - 30720;
            int r = j / 160, c = j % 160;
            float v = (c < DM_) ? Wl[r * DM_ + c] : (c == DM_ ? lb[r] : 0.f);
            Wlp[j] = f2bf(v);
        }
        return;
    }
    // ---- KV part ----
    const int kt = bid & 31, h = (bid >> 5) % H_, b = bid / (32 * H_);
    const int bh = b * H_ + h;
    const size_t tile = (size_t)(bh * 32 + kt);
    const float4* Ks = (const float4*)(K + ((size_t)bh * S_ + kt * 64) * DK_);
    ushort* Ko = Ktt + tile * 2048;
    for (int idx = t; idx < 384; idx += 256) {
        int r = idx / 6, c4 = (idx % 6) * 4;
        float4 v = Ks[idx];
        ushort4 u; u.x = f2bf(v.x); u.y = f2bf(v.y); u.z = f2bf(v.z); u.w = f2bf(v.w);
        *(ushort4*)&Ko[r * 32 + c4] = u;
    }
    if (t < 64) { uint4 z = {0u,0u,0u,0u}; *(uint4*)&Ko[t * 32 + 24] = z; }
    const float4* Vs = (const float4*)(V + ((size_t)bh * S_ + kt * 64) * DK_);
    for (int idx = t; idx < 384; idx += 256) {
        int r = idx / 6, c4 = (idx % 6) * 4;
        *(float4*)&sv[r * 25 + c4] = Vs[idx];
    }
    __syncthreads();
    int d = t >> 3, s8 = (t & 7) * 8;
    uint4 o = {0u,0u,0u,0u};
    if (d < DK_) {
        o.x = pack2(sv[(s8 + 0) * 25 + d], sv[(s8 + 1) * 25 + d]);
        o.y = pack2(sv[(s8 + 2) * 25 + d], sv[(s8 + 3) * 25 + d]);
        o.z = pack2(sv[(s8 + 4) * 25 + d], sv[(s8 + 5) * 25 + d]);
        o.w = pack2(sv[(s8 + 6) * 25 + d], sv[(s8 + 7) * 25 + d]);
    }
    ((uint4*)Vtt)[tile * 256 + t] = o;
}

// ---------------------------------------------------------------------------
// attn: fused qproj + tanh-attention.
// Block = 512 threads (8 waves) = 128 q-rows of one (b,h); wave owns 16 rows.
// Grid 768 = 3 blocks/CU, LDS 29KB, 24 waves/CU.
// K/V LDS double-buffer, ONE barrier per k-tile; staging split: waves 0-3
// stage K, waves 4-7 stage V (1 uint4 load+store per thread per tile).
// P never touches LDS: QK^T frag -> PV A-frag via permlane32/16 butterfly.
// Output: bf16 ctx tile into Cb[16384][160] (outln-staging layout).
// ---------------------------------------------------------------------------
__global__ __launch_bounds__(512, 6)
void attn_kernel(const float* __restrict__ Q, const ushort* __restrict__ Whq,
                 const ushort* __restrict__ Ktt, const ushort* __restrict__ Vtt,
                 ushort* __restrict__ Cb) {
    __shared__ __attribute__((aligned(16))) char smem[29696];
    ushort* s_q  = (ushort*)smem;             // 128 x pitch40   [0, 10240)
    ushort* s_k  = (ushort*)(smem + 10240);   // 2 x 64 x pitch40 [10240, 20480)
    ushort* s_vt = (ushort*)(smem + 20480);   // 2 x 32 x pitch72 [20480, 29696)
    float*  s_ctx = (float*)smem;             // epilogue alias: 128 x 28 f32

    const int t = threadIdx.x;
    const int w = t >> 6, n16 = t & 15, g = (t >> 4) & 3;
    const bool hi16 = (t & 16) != 0;
    const int qp = blockIdx.x, h = blockIdx.y, b = blockIdx.z;
    const int bh = b * H_ + h;
    const int row0 = qp * 128;

    const uint4* Kb4 = (const uint4*)Ktt + (size_t)bh * 8192;   // 32 tiles x 256
    const uint4* Vb4 = (const uint4*)Vtt + (size_t)bh * 8192;

    // staging role: waves 0-3 -> K (t<256), waves 4-7 -> V
    const int t2 = t & 255;
    const int stoff = (t < 256) ? ((t2 >> 2) * 40 + (t2 & 3) * 8)
                                : ((t2 >> 3) * 72 + (t2 & 7) * 8);
    uint4 sreg = (t < 256) ? Kb4[t2] : Vb4[t2];       // preload tile 0

    // ---- Phase A: q = Q @ Whq^T + bias (k=144 col), frags from global ----
    const f32x4 zf = {0.f, 0.f, 0.f, 0.f};
    const uint4* Wh4 = (const uint4*)Whq + h * 640;
    {
        const float* Qr = Q + (size_t)(b * S_ + row0 + w * 16 + n16) * DM_;
        f32x4 qa0 = zf, qa1 = zf;
#pragma unroll
        for (int ks = 0; ks < 5; ++ks) {
            bf16x8 av;
            if (ks < 4 || g < 2) {            // real cols (ks=4,g<2 -> 128..143)
                float4 f0 = *(const float4*)&Qr[ks * 32 + g * 8];
                float4 f1 = *(const float4*)&Qr[ks * 32 + g * 8 + 4];
                uint4 u;
                u.x = pack2(f0.x, f0.y); u.y = pack2(f0.z, f0.w);
                u.z = pack2(f1.x, f1.y); u.w = pack2(f1.z, f1.w);
                av = __builtin_bit_cast(bf16x8, u);
            } else {                          // k=144 bias col (g==2), zeros (g==3)
                uint4 u = {0u, 0u, 0u, 0u};
                if (g == 2) u.x = 0x00003F80u;
                av = __builtin_bit_cast(bf16x8, u);
            }
            bf16x8 bv0 = __builtin_bit_cast(bf16x8, Wh4[n16 * 20 + ks * 4 + g]);
            bf16x8 bv1 = __builtin_bit_cast(bf16x8, Wh4[(16 + n16) * 20 + ks * 4 + g]);
            qa0 = MFMA_(av, bv0, qa0, 0, 0, 0);
            qa1 = MFMA_(av, bv1, qa1, 0, 0, 0);
        }
#pragma unroll
        for (int reg = 0; reg < 4; ++reg) {   // wave-local transpose (no barrier)
            int r = (w * 16 + g * 4 + reg) * 40;
            s_q[r + n16]      = f2bf(qa0[reg]);
            s_q[r + 16 + n16] = f2bf(qa1[reg]);   // d 24..31 zero via Whq rows
        }
    }
    const bf16x8 qf = *(const bf16x8*)&s_q[(w * 16 + n16) * 40 + g * 8];

    // ---- k-tile loop: double-buffered LDS, one barrier per tile ----------
    const int aoff = n16 * 40 + g * 8;        // hoisted LDS read offsets
    const int voff = n16 * 72 + g * 8;
    f32x4 acc0 = zf, acc1 = zf;
    // explicit double-buffer pointers (swap each tile)
    ushort* stb_a = ((t < 256) ? s_k : s_vt) + stoff;
    ushort* stb_b = stb_a + ((t < 256) ? 2560 : 2304);
    const ushort* ka = s_k;  const ushort* kb = s_k + 2560;
    const ushort* va = s_vt; const ushort* vbp = s_vt + 2304;
    for (int kt = 0; kt < 32; ++kt) {
        *(uint4*)stb_a = sreg;
        __syncthreads();
        {   // prefetch next tile AFTER the barrier
            int nt = ((kt + 1) & 31) * 256;
            sreg = (t < 256) ? Kb4[nt + t2] : Vb4[nt + t2];
        }
        // S strips -> P in registers
        bf16x8 a0 = *(const bf16x8*)&ka[aoff];
        bf16x8 a1 = *(const bf16x8*)&ka[640 + aoff];
        bf16x8 a2 = *(const bf16x8*)&ka[1280 + aoff];
        bf16x8 a3 = *(const bf16x8*)&ka[1920 + aoff];
        __builtin_amdgcn_s_setprio(1);
        f32x4 c0 = MFMA_(a0, qf, zf, 0, 0, 0);
        f32x4 c1 = MFMA_(a1, qf, zf, 0, 0, 0);
        f32x4 c2 = MFMA_(a2, qf, zf, 0, 0, 0);
        f32x4 c3 = MFMA_(a3, qf, zf, 0, 0, 0);
        __builtin_amdgcn_s_setprio(0);
        // tanh -> packed bf16 words: W[strip][pair], lane holds
        // P[q=n16][s = strip*16 + g*4 + 2*pair + {0,1}]
        uint W0p0 = tanh2_pack(c0[0], c0[1]);
        uint W0p1 = tanh2_pack(c0[2], c0[3]);
        uint W1p0 = tanh2_pack(c1[0], c1[1]);
        uint W1p1 = tanh2_pack(c1[2], c1[3]);
        uint W2p0 = tanh2_pack(c2[0], c2[1]);
        uint W2p1 = tanh2_pack(c2[2], c2[3]);
        uint W3p0 = tanh2_pack(c3[0], c3[1]);
        uint W3p1 = tanh2_pack(c3[2], c3[3]);
        // butterfly: bit5 (strip-pair) then bit4 -> PV A-frags in-register.
        // ap0 lane g = P[q=n16][s=g*8+0..7], ap1 = s=32+g*8+0..7.
        swap32(W0p0, W1p0);                  // x01/y01 (p=0)
        swap32(W2p0, W3p0);                  // x23/y23 (p=0)
        swap32(W0p1, W1p1);                  // p=1
        swap32(W2p1, W3p1);
        swap16(W0p0, W1p0, hi16);            // -> ap0 slotA/slotB (p=0)
        swap16(W2p0, W3p0, hi16);            // -> ap1 slotA/slotB (p=0)
        swap16(W0p1, W1p1, hi16);            // p=1
        swap16(W2p1, W3p1, hi16);
        uint4 ap0u, ap1u;
        ap0u.x = W0p0; ap0u.y = W0p1; ap0u.z = W1p0; ap0u.w = W1p1;
        ap1u.x = W2p0; ap1u.y = W2p1; ap1u.z = W3p0; ap1u.w = W3p1;
        bf16x8 ap0 = __builtin_bit_cast(bf16x8, ap0u);
        bf16x8 ap1 = __builtin_bit_cast(bf16x8, ap1u);
        // PV
        bf16x8 vb00 = *(const bf16x8*)&va[voff];
        bf16x8 vb01 = *(const bf16x8*)&va[voff + 32];
        bf16x8 vb10 = *(const bf16x8*)&va[1152 + voff];
        bf16x8 vb11 = *(const bf16x8*)&va[1152 + voff + 32];
        __builtin_amdgcn_s_setprio(1);
        acc0 = MFMA_(ap0, vb00, acc0, 0, 0, 0);
        acc0 = MFMA_(ap1, vb01, acc0, 0, 0, 0);
        acc1 = MFMA_(ap0, vb10, acc1, 0, 0, 0);
        acc1 = MFMA_(ap1, vb11, acc1, 0, 0, 0);
        __builtin_amdgcn_s_setprio(0);
        // swap double-buffer pointers
        { ushort* tp = stb_a; stb_a = stb_b; stb_b = tp; }
        { const ushort* tp = ka; ka = kb; kb = tp; }
        { const ushort* tp = va; va = vbp; vbp = tp; }
    }

    // ---- epilogue: ctx -> Cb bf16 (s_ctx aliases s_q/s_k; barrier both) ---
    __syncthreads();
#pragma unroll
    for (int reg = 0; reg < 4; ++reg) {
        int row = w * 16 + g * 4 + reg;
        s_ctx[row * 28 + n16] = acc0[reg];
        if (n16 < 8) s_ctx[row * 28 + 16 + n16] = acc1[reg];
    }
    __syncthreads();
    if (t < 384) {
        int r = t / 3, c = t % 3;             // 3 x uint4 (8 bf16) per row
        const float* src = &s_ctx[r * 28 + c * 8];
        uint4 u;
        u.x = pack2(src[0], src[1]); u.y = pack2(src[2], src[3]);
        u.z = pack2(src[4], src[5]); u.w = pack2(src[6], src[7]);
        *(uint4*)&Cb[(size_t)(b * S_ + row0 + r) * 160 + h * 24 + c * 8] = u;
    }
}

// ---------------------------------------------------------------------------
// outln: out = LN(ctx @ Wl^T + lb + residual) * g + beta.
// ctx comes in as bf16 Cb[16384][160] -> pure uint4 LDS staging.
// ---------------------------------------------------------------------------
__global__ __launch_bounds__(512)
void outln_kernel(const float* __restrict__ Qres, const ushort* __restrict__ Wlp,
                  const ushort* __restrict__ Cb,
                  const float* __restrict__ lg, const float* __restrict__ lbeta,
                  float* __restrict__ io) {
    __shared__ __attribute__((aligned(16))) ushort s_a[64 * 168];
    __shared__ __attribute__((aligned(16))) ushort s_w[144 * 168];
    __shared__ float s_red[2][2][64];
    const int t = threadIdx.x;
    const int w = t >> 6, n16 = t & 15, g = (t >> 4) & 3;
    const int wq = w & 3, half = w >> 2;
    const int nt_base = half * 5, nt_cnt = half ? 4 : 5;
    const int row0 = blockIdx.x * 64;

    const ushort* Cr = Cb + (size_t)row0 * 160;
    for (int idx = t; idx < 1152; idx += 512) {     // cols 0..143 only
        int r = idx / 18, c8 = (idx % 18) * 8;
        *(uint4*)&s_a[r * 168 + c8] = *(const uint4*)&Cr[r * 160 + c8];
    }
    if (t < 64) {
        uint4 pad = {0x00003F80u, 0u, 0u, 0u};
        uint4 z4  = {0u, 0u, 0u, 0u};
        *(uint4*)&s_a[t * 168 + 144] = pad;
        *(uint4*)&s_a[t * 168 + 152] = z4;
    }
    for (int idx = t; idx < 2880; idx += 512) {
        int r = idx / 20, c8 = (idx % 20) * 8;
        *(uint4*)&s_w[r * 168 + c8] = *(const uint4*)&Wlp[r * 160 + c8];
    }
    __syncthreads();

    f32x4 acc[5];
#pragma unroll
    for (int j = 0; j < 5; ++j) acc[j] = (f32x4){0.f, 0.f, 0.f, 0.f};
#pragma unroll
    for (int ks = 0; ks < 5; ++ks) {
        bf16x8 av = *(const bf16x8*)&s_a[(wq * 16 + n16) * 168 + ks * 32 + g * 8];
        for (int j = 0; j < nt_cnt; ++j) {
            bf16x8 bv = *(const bf16x8*)&s_w[((nt_base + j) * 16 + n16) * 168 + ks * 32 + g * 8];
            acc[j] = MFMA_(av, bv, acc[j], 0, 0, 0);
        }
    }
    float vals[5][4], s1[4] = {0, 0, 0, 0}, s2[4] = {0, 0, 0, 0};
    for (int j = 0; j < nt_cnt; ++j) {
        int d = (nt_base + j) * 16 + n16;
#pragma unroll
        for (int reg = 0; reg < 4; ++reg) {
            int row = row0 + wq * 16 + g * 4 + reg;
            float v = acc[j][reg] + Qres[(size_t)row * DM_ + d];
            vals[j][reg] = v;
            s1[reg] += v; s2[reg] = fmaf(v, v, s2[reg]);
        }
    }
#pragma unroll
    for (int off = 1; off < 16; off <<= 1) {
#pragma unroll
        for (int reg = 0; reg < 4; ++reg) {
            s1[reg] += __shfl_xor(s1[reg], off);
            s2[reg] += __shfl_xor(s2[reg], off);
        }
    }
    if (n16 == 0) {
#pragma unroll
        for (int reg = 0; reg < 4; ++reg) {
            int rr = wq * 16 + g * 4 + reg;
            s_red[half][0][rr] = s1[reg];
            s_red[half][1][rr] = s2[reg];
        }
    }
    __syncthreads();
    float mu[4], rs[4];
#pragma unroll
    for (int reg = 0; reg < 4; ++reg) {
        int rr = wq * 16 + g * 4 + reg;
        float S1 = s_red[0][0][rr] + s_red[1][0][rr];
        float S2 = s_red[0][1][rr] + s_red[1][1][rr];
        float m = S1 * (1.f / 144.f);
        mu[reg] = m;
        rs[reg] = rsqrtf(S2 * (1.f / 144.f) - m * m + 1e-5f);
    }
    for (int j = 0; j < nt_cnt; ++j) {
        int d = (nt_base + j) * 16 + n16;
        float gv = lg[d], bv = lbeta[d];
#pragma unroll
        for (int reg = 0; reg < 4; ++reg) {
            int row = row0 + wq * 16 + g * 4 + reg;
            io[(size_t)row * DM_ + d] = (vals[j][reg] - mu[reg]) * rs[reg] * gv + bv;
        }
    }
}

// ---------------------------------------------------------------------------
extern "C" void kernel_launch(void* const* d_in, const int* in_sizes, int n_in,
                              void* d_out, int out_size, void* d_ws, size_t ws_size,
                              hipStream_t stream) {
    const float* Q     = (const float*)d_in[0];
    const float* K     = (const float*)d_in[1];
    const float* V     = (const float*)d_in[2];
    // d_in[3] = attn_mask: dead code in the reference, ignored.
    const float* Wq_w  = (const float*)d_in[4];
    const float* Wq_b  = (const float*)d_in[5];
    const float* lin_w = (const float*)d_in[6];
    const float* lin_b = (const float*)d_in[7];
    const float* ln_g  = (const float*)d_in[8];
    const float* ln_b  = (const float*)d_in[9];
    float* out = (float*)d_out;

    ushort* Ktt = (ushort*)d_ws;                            // 6,291,456 B
    ushort* Vtt = (ushort*)((char*)d_ws + 6291456);         // 6,291,456 B
    ushort* Whq = (ushort*)((char*)d_ws + 12582912);        // 61,440 B
    ushort* Wlp = (ushort*)((char*)d_ws + 12644352);        // 46,080 B
    ushort* Cb  = (ushort*)((char*)d_ws + 12690432);        // 5,242,880 B

    prep_kernel<<<1746, 256, 0, stream>>>(K, V, Wq_w, Wq_b, lin_w, lin_b,
                                          Ktt, Vtt, Whq, Wlp);
    attn_kernel<<<dim3(S_ / 128, H_, B_), 512, 0, stream>>>(Q, Whq, Ktt, Vtt, Cb);
    outln_kernel<<<(B_ * S_) / 64, 512, 0, stream>>>(Q, Wlp, Cb, ln_g, ln_b, out);
}